// Round 1
// baseline (394.418 us; speedup 1.0000x reference)
//
#include <hip/hip_runtime.h>
#include <hip/hip_bf16.h>

// Problem: masked-softmax attention.
//   S = Q K^T / sqrt(D); P = masked softmax rows of S; O = P V.
// NQ=8192, NK=2048, D=2048, DV=2048, all fp32 in/out; bf16 MFMA internally.

#define NQ 8192
#define NK 2048
#define DD 2048
#define DVV 2048

typedef __attribute__((ext_vector_type(8))) short short8;   // 8 bf16 (4 VGPRs)
typedef __attribute__((ext_vector_type(4))) float f32x4;    // MFMA accumulator

typedef __attribute__((address_space(3))) void as3_void;
typedef __attribute__((address_space(1))) const void as1_cvoid;
// size arg must be a literal constant for global_load_lds
#define GLOAD16(g, l) __builtin_amdgcn_global_load_lds((as1_cvoid*)(g), (as3_void*)(l), 16, 0, 0)

// ---------------------------------------------------------------- fp32 -> bf16
__global__ __launch_bounds__(256) void conv_bf16_kernel(
    __hip_bfloat16* __restrict__ dst, const float* __restrict__ src, int n4)
{
    int stride = gridDim.x * blockDim.x;
    for (int i = blockIdx.x * blockDim.x + threadIdx.x; i < n4; i += stride) {
        float4 f = reinterpret_cast<const float4*>(src)[i];
        union { __hip_bfloat16 h[4]; uint2 u; } p;
        p.h[0] = __float2bfloat16(f.x);
        p.h[1] = __float2bfloat16(f.y);
        p.h[2] = __float2bfloat16(f.z);
        p.h[3] = __float2bfloat16(f.w);
        reinterpret_cast<uint2*>(dst)[i] = p.u;
    }
}

// ------------------------------------------- V [NK][DV] fp32 -> V^T [DV][NK] bf16
__global__ __launch_bounds__(256) void transpose_conv_kernel(
    __hip_bfloat16* __restrict__ Vt, const float* __restrict__ V)
{
    __shared__ __hip_bfloat16 tile[64][65];   // +1 pad breaks bank-stride
    const int tx = threadIdx.x;               // 0..63
    const int ty = threadIdx.y;               // 0..3
    const int r0 = blockIdx.y * 64;           // NK dim
    const int c0 = blockIdx.x * 64;           // DV dim
    #pragma unroll
    for (int j = ty; j < 64; j += 4)
        tile[j][tx] = __float2bfloat16(V[(size_t)(r0 + j) * DVV + c0 + tx]);
    __syncthreads();
    #pragma unroll
    for (int j = ty; j < 64; j += 4)
        Vt[(size_t)(c0 + j) * NK + r0 + tx] = tile[tx][j];
}

// -------------------------------------------------------------- NT bf16 GEMM
// C[M][N] fp32 = scale * A[M][K](bf16,lda) * B[N][K]^T(bf16,ldb)
// m97 structure: 128x128 tile, BK=64, 4 waves (2x2 of 64x64), global_load_lds
// width-16 staging into linear LDS, 2 barriers per K-step.
__global__ __launch_bounds__(256) void gemm_nt_kernel(
    float* __restrict__ C,
    const __hip_bfloat16* __restrict__ A,
    const __hip_bfloat16* __restrict__ B,
    int K, int lda, int ldb, int ldc, float scale)
{
    constexpr int BM = 128, BN = 128, BK = 64;
    __shared__ __align__(16) __hip_bfloat16 As[BM * BK];   // 16 KB
    __shared__ __align__(16) __hip_bfloat16 Bs[BN * BK];   // 16 KB

    const int tid  = threadIdx.x;
    const int wave = tid >> 6;
    const int lane = tid & 63;
    const int wm   = wave >> 1;          // wave's 64x64 sub-tile
    const int wn   = wave & 1;
    const int bn   = blockIdx.x;         // N fastest -> consecutive blocks share A panel (L2)
    const int bm   = blockIdx.y;

    f32x4 acc[4][4];
    #pragma unroll
    for (int i = 0; i < 4; ++i)
        #pragma unroll
        for (int j = 0; j < 4; ++j)
            acc[i][j] = (f32x4){0.f, 0.f, 0.f, 0.f};

    // staging: chunk = r*256 + tid (16B each); row = chunk>>3, col16 = chunk&7
    const int arow = tid >> 3;
    const int acol = (tid & 7) * 8;
    const __hip_bfloat16* Abase = A + (size_t)(bm * BM + arow) * lda + acol;
    const __hip_bfloat16* Bbase = B + (size_t)(bn * BN + arow) * ldb + acol;

    const int fr = lane & 15;            // fragment row (A) / col (B)
    const int kb = (lane >> 4) << 3;     // k sub-offset 0/8/16/24

    for (int kt = 0; kt < K; kt += BK) {
        __syncthreads();                 // prior reads done before overwrite
        #pragma unroll
        for (int r = 0; r < 4; ++r) {
            // LDS base is wave-uniform; HW scatters lane*16B
            GLOAD16(Abase + (size_t)(r * 32) * lda + kt, &As[(r * 256 + (wave << 6)) * 8]);
            GLOAD16(Bbase + (size_t)(r * 32) * ldb + kt, &Bs[(r * 256 + (wave << 6)) * 8]);
        }
        __syncthreads();                 // drains vmcnt -> tiles ready

        #pragma unroll
        for (int kk = 0; kk < 2; ++kk) {
            short8 af[4], bfv[4];
            #pragma unroll
            for (int mi = 0; mi < 4; ++mi)
                af[mi] = *(const short8*)&As[(wm * 64 + mi * 16 + fr) * BK + kk * 32 + kb];
            #pragma unroll
            for (int ni = 0; ni < 4; ++ni)
                bfv[ni] = *(const short8*)&Bs[(wn * 64 + ni * 16 + fr) * BK + kk * 32 + kb];
            #pragma unroll
            for (int mi = 0; mi < 4; ++mi)
                #pragma unroll
                for (int ni = 0; ni < 4; ++ni)
                    acc[mi][ni] = __builtin_amdgcn_mfma_f32_16x16x32_bf16(
                        af[mi], bfv[ni], acc[mi][ni], 0, 0, 0);
        }
    }

    // C/D layout (verified): col = lane&15, row = (lane>>4)*4 + reg
    const int crow = bm * BM + wm * 64 + ((lane >> 4) << 2);
    const int ccol = bn * BN + wn * 64 + fr;
    #pragma unroll
    for (int mi = 0; mi < 4; ++mi)
        #pragma unroll
        for (int ni = 0; ni < 4; ++ni)
            #pragma unroll
            for (int r = 0; r < 4; ++r)
                C[(size_t)(crow + mi * 16 + r) * ldc + ccol + ni * 16] = acc[mi][ni][r] * scale;
}

// ------------------------------------------- masked softmax row, P bf16 in-place
// att_k = mask_k*exp(s_k - m) / sum_j mask_j*exp(s_j - m)
// P written as bf16 into first half of each fp32 S row (row stride 2*NK bf16).
__global__ __launch_bounds__(256) void softmax_mask_kernel(
    float* __restrict__ S, const float* __restrict__ mask)
{
    const int q    = blockIdx.x;
    const int t    = threadIdx.x;
    const int wave = t >> 6;
    const int lane = t & 63;

    const float4* srow = (const float4*)(S + (size_t)q * NK);
    const float4* mrow = (const float4*)(mask + (size_t)q * NK);
    float4 s0 = srow[t], s1 = srow[t + 256];
    float4 m0 = mrow[t], m1 = mrow[t + 256];

    float mx = fmaxf(fmaxf(fmaxf(s0.x, s0.y), fmaxf(s0.z, s0.w)),
                     fmaxf(fmaxf(s1.x, s1.y), fmaxf(s1.z, s1.w)));
    #pragma unroll
    for (int off = 32; off > 0; off >>= 1)
        mx = fmaxf(mx, __shfl_xor(mx, off));

    __shared__ float redm[4], reds[4];
    if (lane == 0) redm[wave] = mx;
    __syncthreads();
    mx = fmaxf(fmaxf(redm[0], redm[1]), fmaxf(redm[2], redm[3]));

    float e[8];
    e[0] = __expf(s0.x - mx) * m0.x;
    e[1] = __expf(s0.y - mx) * m0.y;
    e[2] = __expf(s0.z - mx) * m0.z;
    e[3] = __expf(s0.w - mx) * m0.w;
    e[4] = __expf(s1.x - mx) * m1.x;
    e[5] = __expf(s1.y - mx) * m1.y;
    e[6] = __expf(s1.z - mx) * m1.z;
    e[7] = __expf(s1.w - mx) * m1.w;

    float sum = ((e[0] + e[1]) + (e[2] + e[3])) + ((e[4] + e[5]) + (e[6] + e[7]));
    #pragma unroll
    for (int off = 32; off > 0; off >>= 1)
        sum += __shfl_xor(sum, off);
    if (lane == 0) reds[wave] = sum;
    __syncthreads();
    sum = (reds[0] + reds[1]) + (reds[2] + reds[3]);
    const float inv = 1.0f / sum;

    __hip_bfloat16* prow = reinterpret_cast<__hip_bfloat16*>(S) + (size_t)q * (2 * NK);
    union { __hip_bfloat16 h[4]; uint2 u; } p;
    p.h[0] = __float2bfloat16(e[0] * inv);
    p.h[1] = __float2bfloat16(e[1] * inv);
    p.h[2] = __float2bfloat16(e[2] * inv);
    p.h[3] = __float2bfloat16(e[3] * inv);
    reinterpret_cast<uint2*>(prow)[t] = p.u;
    p.h[0] = __float2bfloat16(e[4] * inv);
    p.h[1] = __float2bfloat16(e[5] * inv);
    p.h[2] = __float2bfloat16(e[6] * inv);
    p.h[3] = __float2bfloat16(e[7] * inv);
    reinterpret_cast<uint2*>(prow)[t + 256] = p.u;
}

// ---------------------------------------------------------------------- launch
extern "C" void kernel_launch(void* const* d_in, const int* in_sizes, int n_in,
                              void* d_out, int out_size, void* d_ws, size_t ws_size,
                              hipStream_t stream)
{
    const float* Q    = (const float*)d_in[0];
    const float* Km   = (const float*)d_in[1];
    const float* V    = (const float*)d_in[2];
    const float* mask = (const float*)d_in[3];
    float* out = (float*)d_out;

    char* ws = (char*)d_ws;
    __hip_bfloat16* Qb  = (__hip_bfloat16*)ws;                               // 32 MB
    __hip_bfloat16* Kb  = (__hip_bfloat16*)(ws + (size_t)32 * 1024 * 1024);  //  8 MB
    __hip_bfloat16* Vtb = (__hip_bfloat16*)(ws + (size_t)40 * 1024 * 1024);  //  8 MB
    float*          S   = (float*)        (ws + (size_t)48 * 1024 * 1024);   // 64 MB

    conv_bf16_kernel<<<2048, 256, 0, stream>>>(Qb, Q, NQ * DD / 4);
    conv_bf16_kernel<<<1024, 256, 0, stream>>>(Kb, Km, NK * DD / 4);
    transpose_conv_kernel<<<dim3(DVV / 64, NK / 64), dim3(64, 4), 0, stream>>>(Vtb, V);

    const float scale = 0.022097086912079608f;  // 1/sqrt(2048)
    // S = scale * Qb * Kb^T
    gemm_nt_kernel<<<dim3(NK / 128, NQ / 128), 256, 0, stream>>>(
        S, Qb, Kb, DD, DD, DD, NK, scale);
    // masked softmax; P bf16 in-place (row stride 2*NK bf16 elements)
    softmax_mask_kernel<<<NQ, 256, 0, stream>>>(S, mask);
    // out = P * (V^T)^T
    gemm_nt_kernel<<<dim3(DVV / 128, NQ / 128), 256, 0, stream>>>(
        out, (const __hip_bfloat16*)S, Vtb, NK, 2 * NK, NK, DVV, 1.0f);
}

// Round 2
// 330.755 us; speedup vs baseline: 1.1925x; 1.1925x over previous
//
#include <hip/hip_runtime.h>
#include <hip/hip_bf16.h>

// Masked-softmax attention: S = Q K^T / sqrt(D); P = masked softmax; O = P V.
// NQ=8192, NK=2048, D=2048, DV=2048; fp32 in/out, bf16 MFMA internally.
// GEMMs: 256x256 8-phase schedule (T1+T2+T3+T4+T5 per guide §5/§5.5).

#define NQ 8192
#define NK 2048
#define DD 2048
#define DVV 2048

typedef __attribute__((ext_vector_type(8))) short short8;   // 8 bf16
typedef __attribute__((ext_vector_type(4))) float f32x4;    // MFMA acc

typedef __attribute__((address_space(3))) void as3_void;
typedef __attribute__((address_space(1))) const void as1_cvoid;
#define GLOAD16(g, l) __builtin_amdgcn_global_load_lds((as1_cvoid*)(g), (as3_void*)(l), 16, 0, 0)

#define SBAR do { __builtin_amdgcn_sched_barrier(0); __builtin_amdgcn_s_barrier(); } while (0)
#define WLG0 do { asm volatile("s_waitcnt lgkmcnt(0)" ::: "memory"); __builtin_amdgcn_sched_barrier(0); } while (0)

// ---------------------------------------------------------------- fp32 -> bf16
__global__ __launch_bounds__(256) void conv_bf16_kernel(
    __hip_bfloat16* __restrict__ dst, const float* __restrict__ src, int n4)
{
    int stride = gridDim.x * blockDim.x;
    for (int i = blockIdx.x * blockDim.x + threadIdx.x; i < n4; i += stride) {
        float4 f = reinterpret_cast<const float4*>(src)[i];
        union { __hip_bfloat16 h[4]; uint2 u; } p;
        p.h[0] = __float2bfloat16(f.x);
        p.h[1] = __float2bfloat16(f.y);
        p.h[2] = __float2bfloat16(f.z);
        p.h[3] = __float2bfloat16(f.w);
        reinterpret_cast<uint2*>(dst)[i] = p.u;
    }
}

// ------------------------------------------- V [NK][DV] fp32 -> V^T [DV][NK] bf16
__global__ __launch_bounds__(256) void transpose_conv_kernel(
    __hip_bfloat16* __restrict__ Vt, const float* __restrict__ V)
{
    __shared__ __hip_bfloat16 tile[64][65];
    const int tx = threadIdx.x;               // 0..63
    const int ty = threadIdx.y;               // 0..3
    const int r0 = blockIdx.y * 64;           // NK dim
    const int c0 = blockIdx.x * 64;           // DV dim
    #pragma unroll
    for (int j = ty; j < 64; j += 4)
        tile[j][tx] = __float2bfloat16(V[(size_t)(r0 + j) * DVV + c0 + tx]);
    __syncthreads();
    #pragma unroll
    for (int j = ty; j < 64; j += 4)
        Vt[(size_t)(c0 + j) * NK + r0 + tx] = tile[tx][j];
}

// ------------------------------------------------------ 256x256 8-phase NT GEMM
// C[M][N] fp32 = scale * A[M][K](bf16,lda) * B[N][K]^T(bf16,ldb)
// 8 waves (2M x 4N), BK=64, LDS 128KB double-buffered, 16B-chunk XOR swizzle
// (chunk ^= row&7) on BOTH staging-source and ds_read (rule #21).
// Per K-tile: 4 quadrant phases; counted vmcnt(4) once per tile (T4).
// Grid MUST be (M/256)*(N/256) with N/256 == 8 (swz decode hardcoded).
__global__ __launch_bounds__(512, 2) void gemm_nt8_kernel(
    float* __restrict__ C,
    const __hip_bfloat16* __restrict__ A,
    const __hip_bfloat16* __restrict__ B,
    int K, int lda, int ldb, int ldc, float scale)
{
    constexpr int BM = 256, BN = 256, BK = 64;
    const int NT = K / BK;
    __shared__ __align__(16) __hip_bfloat16 As[2][BM * BK];   // 2 x 32 KB
    __shared__ __align__(16) __hip_bfloat16 Bs[2][BN * BK];   // 2 x 32 KB

    const int tid  = threadIdx.x;
    const int wave = tid >> 6;
    const int lane = tid & 63;
    const int wm   = wave >> 2;      // 0..1
    const int wn   = wave & 3;       // 0..3
    const int fr   = lane & 15;
    const int fq   = lane >> 4;      // 0..3

    // T1: XCD-aware swizzle (256 blocks, 8 XCDs -> each XCD owns 4 contiguous bm)
    const int swz = (blockIdx.x & 7) * 32 + (blockIdx.x >> 3);
    const int bm  = swz >> 3;
    const int bn  = swz & 7;

    // staging source pre-swizzle: slot (row, c) holds global chunk c ^ (row&7)
    const int srow = tid >> 3;                          // 0..63
    const int scol = (((tid & 7) ^ (srow & 7)) << 3);   // element offset in K-tile

    const __hip_bfloat16* Ab = A + (size_t)(bm * BM) * lda;
    const __hip_bfloat16* Bb = B + (size_t)(bn * BN) * ldb;

    f32x4 acc[8][4];
    #pragma unroll
    for (int i = 0; i < 8; ++i)
        #pragma unroll
        for (int j = 0; j < 4; ++j)
            acc[i][j] = (f32x4){0.f, 0.f, 0.f, 0.f};

    short8 af[4][2], b0[2][2], b1[2][2];

    // one half-tile = 128 rows x 64 cols = 16KB = 2 gloads/thread
    auto stage_a = [&](int pp, int h, int kt) {
        GLOAD16(Ab + (size_t)(h * 128 +      srow) * lda + kt + scol,
                &As[pp][(h * 1024 +       wave * 64) * 8]);
        GLOAD16(Ab + (size_t)(h * 128 + 64 + srow) * lda + kt + scol,
                &As[pp][(h * 1024 + 512 + wave * 64) * 8]);
    };
    auto stage_b = [&](int pp, int h, int kt) {
        GLOAD16(Bb + (size_t)(h * 128 +      srow) * ldb + kt + scol,
                &Bs[pp][(h * 1024 +       wave * 64) * 8]);
        GLOAD16(Bb + (size_t)(h * 128 + 64 + srow) * ldb + kt + scol,
                &Bs[pp][(h * 1024 + 512 + wave * 64) * 8]);
    };
    // fragment reads with the same XOR swizzle; row&7 == fr&7 here
    auto load_a = [&](int pp, int mh) {
        #pragma unroll
        for (int mi = 0; mi < 4; ++mi)
            #pragma unroll
            for (int kk = 0; kk < 2; ++kk) {
                const int row = mh * 128 + wm * 64 + mi * 16 + fr;
                af[mi][kk] = *(const short8*)
                    &As[pp][row * 64 + ((((kk << 2) | fq) ^ (fr & 7)) << 3)];
            }
    };
    auto load_b = [&](int pp, int nh, short8 (&dst)[2][2]) {
        #pragma unroll
        for (int ni = 0; ni < 2; ++ni)
            #pragma unroll
            for (int kk = 0; kk < 2; ++kk) {
                const int row = nh * 128 + wn * 32 + ni * 16 + fr;
                dst[ni][kk] = *(const short8*)
                    &Bs[pp][row * 64 + ((((kk << 2) | fq) ^ (fr & 7)) << 3)];
            }
    };

#define QUAD(mh, nh, bset) do {                                              \
        __builtin_amdgcn_s_setprio(1);                                       \
        _Pragma("unroll")                                                    \
        for (int mi = 0; mi < 4; ++mi)                                       \
            _Pragma("unroll")                                                \
            for (int ni = 0; ni < 2; ++ni)                                   \
                _Pragma("unroll")                                            \
                for (int kk = 0; kk < 2; ++kk)                               \
                    acc[(mh) * 4 + mi][(nh) * 2 + ni] =                      \
                        __builtin_amdgcn_mfma_f32_16x16x32_bf16(             \
                            af[mi][kk], bset[ni][kk],                        \
                            acc[(mh) * 4 + mi][(nh) * 2 + ni], 0, 0, 0);     \
        __builtin_amdgcn_s_setprio(0);                                       \
    } while (0)

    // prologue: tile0 (A0,B0,A1,B1) + tile1 (A0,B0); keep tile1 in flight
    stage_a(0, 0, 0); stage_b(0, 0, 0);
    stage_a(0, 1, 0); stage_b(0, 1, 0);
    if (NT > 1) {
        stage_a(1, 0, BK); stage_b(1, 0, BK);
        asm volatile("s_waitcnt vmcnt(4)" ::: "memory");
    } else {
        asm volatile("s_waitcnt vmcnt(0)" ::: "memory");
    }
    SBAR;

    for (int t = 0; t < NT; ++t) {
        const int p  = t & 1;
        const int q  = p ^ 1;
        const int k1 = (t + 1) * BK;
        const int k2 = (t + 2) * BK;
        // phase 1: quadrant (0,0) — reads A-h0, B-h0
        load_a(p, 0);
        load_b(p, 0, b0);
        if (t + 1 < NT) stage_a(q, 1, k1);      // (t+1).A1 -> other buf
        SBAR; WLG0;
        QUAD(0, 0, b0);
        SBAR;
        // phase 2: quadrant (0,1) — reads B-h1 (A regs reused)
        load_b(p, 1, b1);
        if (t + 1 < NT) stage_b(q, 1, k1);      // (t+1).B1 -> other buf
        SBAR; WLG0;
        QUAD(0, 1, b1);
        SBAR;
        // phase 3: quadrant (1,0) — reads A-h1 (B-h0 regs reused)
        load_a(p, 1);
        if (t + 2 < NT) stage_a(p, 0, k2);      // (t+2).A0 -> live buf, h0 free since ph1
        SBAR; WLG0;
        QUAD(1, 0, b0);
        SBAR;
        // phase 4: quadrant (1,1) — pure reg
        if (t + 2 < NT) stage_b(p, 0, k2);      // (t+2).B0 -> live buf, h0 free since ph1
        SBAR;
        QUAD(1, 1, b1);
        if (t + 2 < NT) { asm volatile("s_waitcnt vmcnt(4)" ::: "memory"); }
        else            { asm volatile("s_waitcnt vmcnt(0)" ::: "memory"); }
        SBAR;                                    // after this, tile t+1 fully in LDS
    }
#undef QUAD

    // epilogue: C/D layout col=lane&15, row=fq*4+reg (dtype-independent, verified)
    #pragma unroll
    for (int mi = 0; mi < 8; ++mi) {
        const int row = bm * BM + (mi >> 2) * 128 + wm * 64 + (mi & 3) * 16 + fq * 4;
        #pragma unroll
        for (int ni = 0; ni < 4; ++ni) {
            const int col = bn * BN + (ni >> 1) * 128 + wn * 32 + (ni & 1) * 16 + fr;
            #pragma unroll
            for (int r = 0; r < 4; ++r)
                C[(size_t)(row + r) * ldc + col] = acc[mi][ni][r] * scale;
        }
    }
}

// ------------------------------------------- masked softmax row, P bf16 in-place
__global__ __launch_bounds__(256) void softmax_mask_kernel(
    float* __restrict__ S, const float* __restrict__ mask)
{
    const int q    = blockIdx.x;
    const int t    = threadIdx.x;
    const int wave = t >> 6;
    const int lane = t & 63;

    const float4* srow = (const float4*)(S + (size_t)q * NK);
    const float4* mrow = (const float4*)(mask + (size_t)q * NK);
    float4 s0 = srow[t], s1 = srow[t + 256];
    float4 m0 = mrow[t], m1 = mrow[t + 256];

    float mx = fmaxf(fmaxf(fmaxf(s0.x, s0.y), fmaxf(s0.z, s0.w)),
                     fmaxf(fmaxf(s1.x, s1.y), fmaxf(s1.z, s1.w)));
    #pragma unroll
    for (int off = 32; off > 0; off >>= 1)
        mx = fmaxf(mx, __shfl_xor(mx, off));

    __shared__ float redm[4], reds[4];
    if (lane == 0) redm[wave] = mx;
    __syncthreads();
    mx = fmaxf(fmaxf(redm[0], redm[1]), fmaxf(redm[2], redm[3]));

    float e[8];
    e[0] = __expf(s0.x - mx) * m0.x;
    e[1] = __expf(s0.y - mx) * m0.y;
    e[2] = __expf(s0.z - mx) * m0.z;
    e[3] = __expf(s0.w - mx) * m0.w;
    e[4] = __expf(s1.x - mx) * m1.x;
    e[5] = __expf(s1.y - mx) * m1.y;
    e[6] = __expf(s1.z - mx) * m1.z;
    e[7] = __expf(s1.w - mx) * m1.w;

    float sum = ((e[0] + e[1]) + (e[2] + e[3])) + ((e[4] + e[5]) + (e[6] + e[7]));
    #pragma unroll
    for (int off = 32; off > 0; off >>= 1)
        sum += __shfl_xor(sum, off);
    if (lane == 0) reds[wave] = sum;
    __syncthreads();
    sum = (reds[0] + reds[1]) + (reds[2] + reds[3]);
    const float inv = 1.0f / sum;

    __hip_bfloat16* prow = reinterpret_cast<__hip_bfloat16*>(S) + (size_t)q * (2 * NK);
    union { __hip_bfloat16 h[4]; uint2 u; } p;
    p.h[0] = __float2bfloat16(e[0] * inv);
    p.h[1] = __float2bfloat16(e[1] * inv);
    p.h[2] = __float2bfloat16(e[2] * inv);
    p.h[3] = __float2bfloat16(e[3] * inv);
    reinterpret_cast<uint2*>(prow)[t] = p.u;
    p.h[0] = __float2bfloat16(e[4] * inv);
    p.h[1] = __float2bfloat16(e[5] * inv);
    p.h[2] = __float2bfloat16(e[6] * inv);
    p.h[3] = __float2bfloat16(e[7] * inv);
    reinterpret_cast<uint2*>(prow)[t + 256] = p.u;
}

// ---------------------------------------------------------------------- launch
extern "C" void kernel_launch(void* const* d_in, const int* in_sizes, int n_in,
                              void* d_out, int out_size, void* d_ws, size_t ws_size,
                              hipStream_t stream)
{
    const float* Q    = (const float*)d_in[0];
    const float* Km   = (const float*)d_in[1];
    const float* V    = (const float*)d_in[2];
    const float* mask = (const float*)d_in[3];
    float* out = (float*)d_out;

    char* ws = (char*)d_ws;
    __hip_bfloat16* Qb  = (__hip_bfloat16*)ws;                               // 32 MB
    __hip_bfloat16* Kb  = (__hip_bfloat16*)(ws + (size_t)32 * 1024 * 1024);  //  8 MB
    __hip_bfloat16* Vtb = (__hip_bfloat16*)(ws + (size_t)40 * 1024 * 1024);  //  8 MB
    float*          S   = (float*)        (ws + (size_t)48 * 1024 * 1024);   // 64 MB

    conv_bf16_kernel<<<2048, 256, 0, stream>>>(Qb, Q, NQ * DD / 4);
    conv_bf16_kernel<<<1024, 256, 0, stream>>>(Kb, Km, NK * DD / 4);
    transpose_conv_kernel<<<dim3(DVV / 64, NK / 64), dim3(64, 4), 0, stream>>>(Vtb, V);

    const float scale = 0.022097086912079608f;  // 1/sqrt(2048)
    // S = scale * Qb * Kb^T   (grid = (8192/256)*(2048/256) = 256)
    gemm_nt8_kernel<<<256, 512, 0, stream>>>(S, Qb, Kb, DD, DD, DD, NK, scale);
    // masked softmax; P bf16 in-place (row stride 2*NK bf16 elements)
    softmax_mask_kernel<<<NQ, 256, 0, stream>>>(S, mask);
    // out = P * (V^T)^T
    gemm_nt8_kernel<<<256, 512, 0, stream>>>(out, (const __hip_bfloat16*)S, Vtb,
                                             NK, 2 * NK, NK, DVV, 1.0f);
}